// Round 2
// 372.669 us; speedup vs baseline: 1.0533x; 1.0533x over previous
//
#include <hip/hip_runtime.h>

// Encoder: B=512, T=128, N=128, H=256
// Round 6: fix W1 stride typo in k_prep_w (k*128, not k*256).
//   k_rnn is the Round-5 MFMA recurrence:
//   32 blocks x 512 thr; block owns 16 batches + full H=256.
//   Wh held in VGPRs as B-frags (16 x hf8 / lane, loaded once from f32 Wh).
//   h ping-pongs in LDS (2 x 8KB), XOR slot-swizzle (slot ^= row&7) so the
//   stride-512B A-frag ds_read_b128 is bank-conflict-free.
//   xw prefetched one timestep ahead; 1 barrier/step; Hb written f16.
//  k_prep_w: Wxt[256][128], W2t[128][256], W1t[128][128] (f16, [n][k] layouts)
//  k_gemm<K,MODE>: C = A @ Bt^T via mfma_f32_16x16x32_f16, Mt=64, Nt=128.
//  k_attn: e_i = sum_tau (-2wv)*rcp(P*Q+1) (+ softmax-invariant const, dropped)
//          pairwise: w0/u+w1/v = (w0 v + w1 u)*rcp(u v); softmax over i; scale.
// Workspace (f32 offsets): P 0 | xw/Q 8388608 | Hb(hf) 25165824 | wts(hf) 33554432
//   => 134,381,568 bytes.

#define C2L 2.8853900817779268f   // 2*log2(e)
#define L2E 1.4426950408889634f   // log2(e)

typedef _Float16 hf;
typedef _Float16 hf2 __attribute__((ext_vector_type(2)));
typedef _Float16 hf4 __attribute__((ext_vector_type(4)));
typedef _Float16 hf8 __attribute__((ext_vector_type(8)));
typedef float f32x4 __attribute__((ext_vector_type(4)));

__device__ __forceinline__ float fast_exp2(float x){
#if __has_builtin(__builtin_amdgcn_exp2f)
  return __builtin_amdgcn_exp2f(x);
#else
  return exp2f(x);
#endif
}
__device__ __forceinline__ float fast_rcp(float x){
#if __has_builtin(__builtin_amdgcn_rcpf)
  return __builtin_amdgcn_rcpf(x);
#else
  return 1.f/x;
#endif
}

// ---------------- weight prep: f32 [k][n] -> f16 [n][k] ----------------
__global__ __launch_bounds__(256) void k_prep_w(const float* __restrict__ Wx,
    const float* __restrict__ W2, const float* __restrict__ W1,
    hf* __restrict__ wts){
  int tid = blockIdx.x*256 + threadIdx.x;   // 320 blocks -> 81920 threads
  if (tid < 32768){                          // Wxt[n<256][k<128]
    int n = tid >> 7, k = tid & 127;
    wts[tid] = (hf)Wx[k*256 + n];
  } else if (tid < 65536){                   // W2t[n<128][k<256]
    int t2 = tid - 32768;
    int n = t2 >> 8, k = t2 & 255;
    wts[tid] = (hf)W2[k*128 + n];
  } else {                                   // W1t[n<128][k<128]
    int t3 = tid - 65536;
    int n = t3 >> 7, k = t3 & 127;
    wts[tid] = (hf)W1[k*128 + n];
  }
}

// ---------------- unified MFMA GEMM ----------------
// block = 256 thr (4 waves). Tile: M=64 (wave strip 16), N=128, K chunked by 128.
// LDS: As[64][136] + Bs[128][136] f16 = 52,224 B.
template<int K, int MODE>
__global__ __launch_bounds__(256) void k_gemm(const void* __restrict__ Asrc,
    const hf* __restrict__ Bt, const float* __restrict__ bias,
    float* __restrict__ Cout){
  constexpr int SA = 136;
  __shared__ alignas(16) hf As[64*SA];
  __shared__ alignas(16) hf Bs[128*SA];
  const int tid = threadIdx.x;
  const int w = tid >> 6, lane = tid & 63;
  const int c = lane & 15, q = lane >> 4;
  const int bx = blockIdx.x;
  const int col0 = (MODE==0) ? blockIdx.y*128 : 0;

  float br[8];
  #pragma unroll
  for (int ni=0; ni<8; ni++) br[ni] = bias[col0 + ni*16 + c];

  f32x4 acc[8];
  #pragma unroll
  for (int ni=0; ni<8; ni++) acc[ni] = (f32x4){0.f,0.f,0.f,0.f};

  for (int kc=0; kc<K/128; kc++){
    // ---- stage A chunk (64 rows x 128 k) ----
    if (MODE == 0){
      const float* A = (const float*)Asrc + (long)bx*64*128;
      #pragma unroll
      for (int v=0; v<8; v++){
        int f4 = v*256 + tid;
        int m = f4 >> 5, k4 = (f4 & 31)*4;
        float4 d = *(const float4*)&A[m*128 + k4];
        hf4 h = {(hf)d.x,(hf)d.y,(hf)d.z,(hf)d.w};
        *(hf4*)&As[m*SA + k4] = h;
      }
    } else if (MODE == 1){
      const hf* A = (const hf*)Asrc + (long)bx*64*256;
      #pragma unroll
      for (int v=0; v<4; v++){
        int f8 = v*256 + tid;
        int m = f8 >> 4, k8 = (f8 & 15)*8;
        *(hf8*)&As[m*SA + k8] = *(const hf8*)&A[m*256 + kc*128 + k8];
      }
    } else {
      const float* A = (const float*)Asrc + (long)(bx>>1)*16384;
      const int i0 = (bx & 1)*64;
      #pragma unroll
      for (int v=0; v<8; v++){
        int f4 = v*256 + tid;
        int t = f4 >> 4, i4 = (f4 & 15)*4;
        float4 d = *(const float4*)&A[t*128 + i0 + i4];
        As[(i4+0)*SA + t] = (hf)d.x;
        As[(i4+1)*SA + t] = (hf)d.y;
        As[(i4+2)*SA + t] = (hf)d.z;
        As[(i4+3)*SA + t] = (hf)d.w;
      }
    }
    // ---- stage B chunk (128 n x 128 k), Bt is f16 [n][K] ----
    #pragma unroll
    for (int v=0; v<8; v++){
      int f8 = v*256 + tid;
      int n = f8 >> 4, k8 = (f8 & 15)*8;
      *(hf8*)&Bs[n*SA + k8] = *(const hf8*)&Bt[(col0+n)*K + kc*128 + k8];
    }
    __syncthreads();
    // ---- MFMA ----
    #pragma unroll
    for (int kk=0; kk<4; kk++){
      hf8 a = *(const hf8*)&As[(w*16 + c)*SA + kk*32 + q*8];
      #pragma unroll
      for (int ni=0; ni<8; ni++){
        hf8 b = *(const hf8*)&Bs[(ni*16 + c)*SA + kk*32 + q*8];
        acc[ni] = __builtin_amdgcn_mfma_f32_16x16x32_f16(a, b, acc[ni], 0, 0, 0);
      }
    }
    __syncthreads();
  }
  // ---- epilogue ----
  #pragma unroll
  for (int ni=0; ni<8; ni++){
    #pragma unroll
    for (int r=0; r<4; r++){
      int rloc = w*16 + q*4 + r;
      int col = col0 + ni*16 + c;
      float val = acc[ni][r] + br[ni];
      int addr;
      if (MODE == 0){
        int R = bx*64 + rloc;
        int b_ = R >> 7, t_ = R & 127;
        addr = (t_*512 + b_)*256 + col;
      } else if (MODE == 1){
        int R = bx*64 + rloc;
        addr = R*128 + col;
        val = fast_exp2(C2L*val);
      } else {
        int b_ = bx >> 1, i_ = (bx & 1)*64 + rloc;
        addr = b_*16384 + i_*128 + col;
        val = fast_exp2(C2L*val);
      }
      Cout[addr] = val;
    }
  }
}

// ---------------- recurrence (MFMA) ----------------
// 32 blocks x 512 thr (8 waves). Block owns batches [16*bx, 16*bx+16) and all
// H=256. Wave w owns output cols [32w, 32w+32): 2 n-tiles x 8 k-chunks of
// mfma_f32_16x16x32_f16, B-frags of Wh^T resident in 64 VGPRs/lane.
// h[16][256] hf ping-pongs in LDS, XOR slot-swizzle: within a 512B row, 16B
// slot s -> s ^ (row&7). A-frag read (row=lane&15, slot=kc*4+q): every
// consecutive-8-lane group covers 8 distinct slot classes -> conflict-free.
// xw prefetched one step ahead; 1 barrier/step.
__global__ __launch_bounds__(512, 2) void k_rnn(const float* __restrict__ h0,
    const float* __restrict__ Wh, const float* __restrict__ xw,
    hf* __restrict__ Hb){
  __shared__ alignas(16) char hs[2*8192];   // [parity][16 rows x 512B]
  const int tid = threadIdx.x;
  const int w = tid >> 6, lane = tid & 63;
  const int c = lane & 15, q = lane >> 4;
  const int b0 = blockIdx.x * 16;
  const int w0 = w * 32;
  // ---- Wh B-frags: bw[nt][kc][e] = Wh[kc*32+q*8+e][w0+nt*16+c] (one-time) ----
  hf8 bw[2][8];
  #pragma unroll
  for (int nt=0; nt<2; nt++){
    #pragma unroll
    for (int kc=0; kc<8; kc++){
      #pragma unroll
      for (int e=0; e<8; e++){
        bw[nt][kc][e] = (hf)Wh[(kc*32 + q*8 + e)*256 + w0 + nt*16 + c];
      }
    }
  }
  // ---- stage h0 -> hs[parity 0], swizzled ----
  {
    int m = tid >> 5, s8 = tid & 31;           // row, 16B-slot
    const float* src = &h0[(b0 + m)*256 + s8*8];
    float4 d0 = *(const float4*)&src[0];
    float4 d1 = *(const float4*)&src[4];
    hf8 hv = {(hf)d0.x,(hf)d0.y,(hf)d0.z,(hf)d0.w,
              (hf)d1.x,(hf)d1.y,(hf)d1.z,(hf)d1.w};
    *(hf8*)&hs[m*512 + ((s8 ^ (m & 7)) << 4)] = hv;
  }
  // ---- prefetch xw for t=0 ----
  float xwv[2][4];
  #pragma unroll
  for (int nt=0; nt<2; nt++){
    #pragma unroll
    for (int r=0; r<4; r++)
      xwv[nt][r] = xw[(b0 + q*4 + r)*256 + w0 + nt*16 + c];
  }
  __syncthreads();
  const int m = c;                 // A-frag row (batch within block)
  const int abase = m*512;
  for (int t=0; t<128; t++){
    const int p = t & 1;
    // prefetch next step's xw (consumed next iteration -> latency hidden)
    float xwn[2][4];
    if (t < 127){
      #pragma unroll
      for (int nt=0; nt<2; nt++){
        #pragma unroll
        for (int r=0; r<4; r++)
          xwn[nt][r] = xw[((t+1)*512 + b0 + q*4 + r)*256 + w0 + nt*16 + c];
      }
    } else {
      #pragma unroll
      for (int nt=0; nt<2; nt++){
        #pragma unroll
        for (int r=0; r<4; r++) xwn[nt][r] = 0.f;
      }
    }
    // ---- A-frags from LDS (swizzled, conflict-free) ----
    hf8 a[8];
    #pragma unroll
    for (int kc=0; kc<8; kc++)
      a[kc] = *(const hf8*)&hs[p*8192 + abase + ((((kc<<2)|q) ^ (m & 7)) << 4)];
    // ---- MFMA: two independent 8-deep accumulation chains ----
    f32x4 acc0 = (f32x4){0.f,0.f,0.f,0.f};
    f32x4 acc1 = (f32x4){0.f,0.f,0.f,0.f};
    #pragma unroll
    for (int kc=0; kc<8; kc++){
      acc0 = __builtin_amdgcn_mfma_f32_16x16x32_f16(a[kc], bw[0][kc], acc0, 0,0,0);
      acc1 = __builtin_amdgcn_mfma_f32_16x16x32_f16(a[kc], bw[1][kc], acc1, 0,0,0);
    }
    // ---- epilogue: tanh, write h -> LDS (other parity) + Hb(global, f16) ----
    #pragma unroll
    for (int nt=0; nt<2; nt++){
      #pragma unroll
      for (int r=0; r<4; r++){
        float v = (nt ? acc1[r] : acc0[r]) + xwv[nt][r];
        float e2 = fast_exp2(v*C2L);
        float hn = 1.f - 2.f*fast_rcp(e2 + 1.f);
        int row = q*4 + r;
        int col = w0 + nt*16 + c;
        *(hf*)&hs[(p^1)*8192 + row*512
                  + (((col >> 3) ^ (row & 7)) << 4) + (col & 7)*2] = (hf)hn;
        Hb[(t*512 + b0 + row)*256 + col] = (hf)hn;
        xwv[nt][r] = xwn[nt][r];
      }
    }
    __syncthreads();
  }
}

// ---------------- attention + softmax + scale ----------------
// grid (512 b, 4 t-tiles), 256 threads. P row halves in registers (64 f32),
// Q tile (32 t) in LDS. Pairwise rcp: w0/u+w1/v = (w0 v + w1 u)*rcp(u*v)
// -> 1 rcp per 2 elements. 4 timesteps per sweep. No max in softmax
// (|e| <= sum|wv| ~ 5). 2 barriers per 4 timesteps (parity buffers).
__global__ __launch_bounds__(256, 4) void k_attn(const float* __restrict__ P,
    const float* __restrict__ Qm, const float* __restrict__ Wv,
    const float* __restrict__ data, float* __restrict__ out){
  __shared__ alignas(16) float qs[32*128];          // [tt][tau] 16KB
  __shared__ alignas(16) float wvs[128];
  __shared__ alignas(16) float epart[2][2][4][128]; // [parity][hl][tl][i] 16KB
  __shared__ float red[2][4][2];                    // [parity][tl][half]
  const int b = blockIdx.x, tile = blockIdx.y;
  const int tid = threadIdx.x;
  const int i = tid & 127, hl = tid >> 7;
  const int t0 = tile*32;
  if (tid < 128) wvs[tid] = -2.f*Wv[tid];
  #pragma unroll
  for (int v=0; v<4; v++){
    int flat = v*1024 + tid*4;
    int tt = flat >> 7, c = flat & 127;
    *(float4*)&qs[flat] = *(const float4*)&Qm[((t0+tt)*512 + b)*128 + c];
  }
  float4 p4[16];
  const float* prow = P + b*16384 + i*128 + hl*64;
  #pragma unroll
  for (int v=0; v<16; v++) p4[v] = *(const float4*)&prow[v*4];
  __syncthreads();
  for (int tp=0; tp<8; tp++){
    const int pp = tp & 1;
    const float* q0r = &qs[(4*tp)*128   + hl*64];
    const float* q1r = &qs[(4*tp+1)*128 + hl*64];
    const float* q2r = &qs[(4*tp+2)*128 + hl*64];
    const float* q3r = &qs[(4*tp+3)*128 + hl*64];
    const float* wvr = &wvs[hl*64];
    float acc0=0.f, acc1=0.f, acc2=0.f, acc3=0.f;
    #pragma unroll
    for (int m=0; m<16; m++){
      float4 Pv = p4[m];
      float4 wv = *(const float4*)&wvr[m*4];
      {
        float4 qq = *(const float4*)&q0r[m*4];
        float u = fmaf(Pv.x, qq.x, 1.f), v = fmaf(Pv.y, qq.y, 1.f);
        float n = fmaf(wv.x, v, wv.y*u);
        acc0 = fmaf(n, fast_rcp(u*v), acc0);
        float u2 = fmaf(Pv.z, qq.z, 1.f), v2 = fmaf(Pv.w, qq.w, 1.f);
        float n2 = fmaf(wv.z, v2, wv.w*u2);
        acc0 = fmaf(n2, fast_rcp(u2*v2), acc0);
      }
      {
        float4 qq = *(const float4*)&q1r[m*4];
        float u = fmaf(Pv.x, qq.x, 1.f), v = fmaf(Pv.y, qq.y, 1.f);
        float n = fmaf(wv.x, v, wv.y*u);
        acc1 = fmaf(n, fast_rcp(u*v), acc1);
        float u2 = fmaf(Pv.z, qq.z, 1.f), v2 = fmaf(Pv.w, qq.w, 1.f);
        float n2 = fmaf(wv.z, v2, wv.w*u2);
        acc1 = fmaf(n2, fast_rcp(u2*v2), acc1);
      }
      {
        float4 qq = *(const float4*)&q2r[m*4];
        float u = fmaf(Pv.x, qq.x, 1.f), v = fmaf(Pv.y, qq.y, 1.f);
        float n = fmaf(wv.x, v, wv.y*u);
        acc2 = fmaf(n, fast_rcp(u*v), acc2);
        float u2 = fmaf(Pv.z, qq.z, 1.f), v2 = fmaf(Pv.w, qq.w, 1.f);
        float n2 = fmaf(wv.z, v2, wv.w*u2);
        acc2 = fmaf(n2, fast_rcp(u2*v2), acc2);
      }
      {
        float4 qq = *(const float4*)&q3r[m*4];
        float u = fmaf(Pv.x, qq.x, 1.f), v = fmaf(Pv.y, qq.y, 1.f);
        float n = fmaf(wv.x, v, wv.y*u);
        acc3 = fmaf(n, fast_rcp(u*v), acc3);
        float u2 = fmaf(Pv.z, qq.z, 1.f), v2 = fmaf(Pv.w, qq.w, 1.f);
        float n2 = fmaf(wv.z, v2, wv.w*u2);
        acc3 = fmaf(n2, fast_rcp(u2*v2), acc3);
      }
    }
    epart[pp][hl][0][i] = acc0;
    epart[pp][hl][1][i] = acc1;
    epart[pp][hl][2][i] = acc2;
    epart[pp][hl][3][i] = acc3;
    __syncthreads();
    const int g = tid >> 7;    // 0/1
    float pe[2];
    #pragma unroll
    for (int s=0; s<2; s++){
      int tl = g + 2*s;        // g=0 -> t 0,2 ; g=1 -> t 1,3
      float e = epart[pp][0][tl][i] + epart[pp][1][tl][i];
      pe[s] = fast_exp2(e*L2E);
      float sm = pe[s];
      #pragma unroll
      for (int off=32; off; off>>=1) sm += __shfl_xor(sm, off);
      if ((tid & 63) == 0) red[pp][tl][(tid>>6)&1] = sm;
    }
    __syncthreads();
    #pragma unroll
    for (int s=0; s<2; s++){
      int tl = g + 2*s;
      float ssum = red[pp][tl][0] + red[pp][tl][1];
      float alpha = pe[s] * fast_rcp(ssum);
      int t = t0 + 4*tp + tl;
      int base = (t*512 + b)*128 + i;
      out[base] = data[base]*alpha;
    }
  }
}

extern "C" void kernel_launch(void* const* d_in, const int* in_sizes, int n_in,
                              void* d_out, int out_size, void* d_ws, size_t ws_size,
                              hipStream_t stream) {
  const float* data = (const float*)d_in[0];
  const float* h0   = (const float*)d_in[1];
  const float* Wx   = (const float*)d_in[2];
  const float* Wh   = (const float*)d_in[3];
  const float* bb   = (const float*)d_in[4];
  const float* W1   = (const float*)d_in[5];
  const float* b1   = (const float*)d_in[6];
  const float* W2   = (const float*)d_in[7];
  const float* b2   = (const float*)d_in[8];
  const float* Wv   = (const float*)d_in[9];
  // d_in[10] = bv: softmax-invariant constant, dropped. d_in[11] = n (128).
  float* wsp = (float*)d_ws;
  float* P   = wsp;                         //  8,388,608 f
  float* xwQ = wsp + 8388608;               // 16,777,216 f (xw, then reused as Q)
  hf*    Hbf = (hf*)(wsp + 25165824);       // 16,777,216 hf
  hf*    wts = (hf*)(wsp + 33554432);       // 81,920 hf
  const hf* Wxt = wts;                      // [256][128]
  const hf* W2t = wts + 32768;              // [128][256]
  const hf* W1t = wts + 65536;              // [128][128]
  float* out = (float*)d_out;

  hipLaunchKernelGGL(k_prep_w, dim3(320), dim3(256), 0, stream, Wx, W2, W1, wts);
  hipLaunchKernelGGL((k_gemm<128,0>), dim3(1024,2), dim3(256), 0, stream,
                     (const void*)data, Wxt, bb, xwQ);
  hipLaunchKernelGGL((k_gemm<128,2>), dim3(1024),   dim3(256), 0, stream,
                     (const void*)data, W1t, b1, P);
  hipLaunchKernelGGL(k_rnn, dim3(32), dim3(512), 0, stream, h0, Wh, xwQ, Hbf);
  hipLaunchKernelGGL((k_gemm<256,1>), dim3(1024),   dim3(256), 0, stream,
                     (const void*)Hbf, W2t, b2, xwQ);
  hipLaunchKernelGGL(k_attn, dim3(512, 4), dim3(256), 0, stream, P, xwQ, Wv, data, out);
}

// Round 3
// 354.216 us; speedup vs baseline: 1.1082x; 1.0521x over previous
//
#include <hip/hip_runtime.h>

// Encoder: B=512, T=128, N=128, H=256
// Round 7:
//  k_attn: 512-thr blocks, thread owns (i, tau-quarter of 32). p4 = 32 VGPR
//          (no AGPR round-trip). 4-way rcp sharing: w0/u+w1/v+w2/x+w3/y =
//          (n01*d23+n23*d01)*rcp(d01*d23) -> 1 rcp per 4 taus (was 1 per 2).
//  k_rnn : 32 blocks x 1024 thr (16 waves); wave owns 16 cols; Wh B-frags
//          32 VGPR/lane; 2x4-deep MFMA chains + f32 add; tanh epilogue 4
//          outputs/thread; h ping-pong LDS with XOR slot-swizzle.
//  k_prep_w: Wxt[256][128], W2t[128][256], W1t[128][128] (f16, [n][k] layouts)
//  k_gemm<K,MODE>: C = A @ Bt^T via mfma_f32_16x16x32_f16, Mt=64, Nt=128.
// Workspace (f32 offsets): P 0 | xw/Q 8388608 | Hb(hf) 25165824 | wts(hf) 33554432
//   => 134,381,568 bytes.

#define C2L 2.8853900817779268f   // 2*log2(e)
#define L2E 1.4426950408889634f   // log2(e)

typedef _Float16 hf;
typedef _Float16 hf2 __attribute__((ext_vector_type(2)));
typedef _Float16 hf4 __attribute__((ext_vector_type(4)));
typedef _Float16 hf8 __attribute__((ext_vector_type(8)));
typedef float f32x4 __attribute__((ext_vector_type(4)));

__device__ __forceinline__ float fast_exp2(float x){
#if __has_builtin(__builtin_amdgcn_exp2f)
  return __builtin_amdgcn_exp2f(x);
#else
  return exp2f(x);
#endif
}
__device__ __forceinline__ float fast_rcp(float x){
#if __has_builtin(__builtin_amdgcn_rcpf)
  return __builtin_amdgcn_rcpf(x);
#else
  return 1.f/x;
#endif
}

// ---------------- weight prep: f32 [k][n] -> f16 [n][k] ----------------
__global__ __launch_bounds__(256) void k_prep_w(const float* __restrict__ Wx,
    const float* __restrict__ W2, const float* __restrict__ W1,
    hf* __restrict__ wts){
  int tid = blockIdx.x*256 + threadIdx.x;   // 320 blocks -> 81920 threads
  if (tid < 32768){                          // Wxt[n<256][k<128]
    int n = tid >> 7, k = tid & 127;
    wts[tid] = (hf)Wx[k*256 + n];
  } else if (tid < 65536){                   // W2t[n<128][k<256]
    int t2 = tid - 32768;
    int n = t2 >> 8, k = t2 & 255;
    wts[tid] = (hf)W2[k*128 + n];
  } else {                                   // W1t[n<128][k<128]
    int t3 = tid - 65536;
    int n = t3 >> 7, k = t3 & 127;
    wts[tid] = (hf)W1[k*128 + n];
  }
}

// ---------------- unified MFMA GEMM ----------------
// block = 256 thr (4 waves). Tile: M=64 (wave strip 16), N=128, K chunked by 128.
// LDS: As[64][136] + Bs[128][136] f16 = 52,224 B.
template<int K, int MODE>
__global__ __launch_bounds__(256) void k_gemm(const void* __restrict__ Asrc,
    const hf* __restrict__ Bt, const float* __restrict__ bias,
    float* __restrict__ Cout){
  constexpr int SA = 136;
  __shared__ alignas(16) hf As[64*SA];
  __shared__ alignas(16) hf Bs[128*SA];
  const int tid = threadIdx.x;
  const int w = tid >> 6, lane = tid & 63;
  const int c = lane & 15, q = lane >> 4;
  const int bx = blockIdx.x;
  const int col0 = (MODE==0) ? blockIdx.y*128 : 0;

  float br[8];
  #pragma unroll
  for (int ni=0; ni<8; ni++) br[ni] = bias[col0 + ni*16 + c];

  f32x4 acc[8];
  #pragma unroll
  for (int ni=0; ni<8; ni++) acc[ni] = (f32x4){0.f,0.f,0.f,0.f};

  for (int kc=0; kc<K/128; kc++){
    // ---- stage A chunk (64 rows x 128 k) ----
    if (MODE == 0){
      const float* A = (const float*)Asrc + (long)bx*64*128;
      #pragma unroll
      for (int v=0; v<8; v++){
        int f4 = v*256 + tid;
        int m = f4 >> 5, k4 = (f4 & 31)*4;
        float4 d = *(const float4*)&A[m*128 + k4];
        hf4 h = {(hf)d.x,(hf)d.y,(hf)d.z,(hf)d.w};
        *(hf4*)&As[m*SA + k4] = h;
      }
    } else if (MODE == 1){
      const hf* A = (const hf*)Asrc + (long)bx*64*256;
      #pragma unroll
      for (int v=0; v<4; v++){
        int f8 = v*256 + tid;
        int m = f8 >> 4, k8 = (f8 & 15)*8;
        *(hf8*)&As[m*SA + k8] = *(const hf8*)&A[m*256 + kc*128 + k8];
      }
    } else {
      const float* A = (const float*)Asrc + (long)(bx>>1)*16384;
      const int i0 = (bx & 1)*64;
      #pragma unroll
      for (int v=0; v<8; v++){
        int f4 = v*256 + tid;
        int t = f4 >> 4, i4 = (f4 & 15)*4;
        float4 d = *(const float4*)&A[t*128 + i0 + i4];
        As[(i4+0)*SA + t] = (hf)d.x;
        As[(i4+1)*SA + t] = (hf)d.y;
        As[(i4+2)*SA + t] = (hf)d.z;
        As[(i4+3)*SA + t] = (hf)d.w;
      }
    }
    // ---- stage B chunk (128 n x 128 k), Bt is f16 [n][K] ----
    #pragma unroll
    for (int v=0; v<8; v++){
      int f8 = v*256 + tid;
      int n = f8 >> 4, k8 = (f8 & 15)*8;
      *(hf8*)&Bs[n*SA + k8] = *(const hf8*)&Bt[(col0+n)*K + kc*128 + k8];
    }
    __syncthreads();
    // ---- MFMA ----
    #pragma unroll
    for (int kk=0; kk<4; kk++){
      hf8 a = *(const hf8*)&As[(w*16 + c)*SA + kk*32 + q*8];
      #pragma unroll
      for (int ni=0; ni<8; ni++){
        hf8 b = *(const hf8*)&Bs[(ni*16 + c)*SA + kk*32 + q*8];
        acc[ni] = __builtin_amdgcn_mfma_f32_16x16x32_f16(a, b, acc[ni], 0, 0, 0);
      }
    }
    __syncthreads();
  }
  // ---- epilogue ----
  #pragma unroll
  for (int ni=0; ni<8; ni++){
    #pragma unroll
    for (int r=0; r<4; r++){
      int rloc = w*16 + q*4 + r;
      int col = col0 + ni*16 + c;
      float val = acc[ni][r] + br[ni];
      int addr;
      if (MODE == 0){
        int R = bx*64 + rloc;
        int b_ = R >> 7, t_ = R & 127;
        addr = (t_*512 + b_)*256 + col;
      } else if (MODE == 1){
        int R = bx*64 + rloc;
        addr = R*128 + col;
        val = fast_exp2(C2L*val);
      } else {
        int b_ = bx >> 1, i_ = (bx & 1)*64 + rloc;
        addr = b_*16384 + i_*128 + col;
        val = fast_exp2(C2L*val);
      }
      Cout[addr] = val;
    }
  }
}

// ---------------- recurrence (MFMA, 16 waves) ----------------
// 32 blocks x 1024 thr. Block owns batches [16*bx,16*bx+16), wave w owns cols
// [16w,16w+16). Wh B-frags: 8 x hf8 = 32 VGPR/lane, loaded once.
// h[16][256] hf ping-pongs in LDS with XOR slot-swizzle (slot ^= row&7):
// A-frag ds_read_b128 conflict-free. 2x4-deep MFMA chains (latency overlap)
// + f32 add. xw prefetched one step ahead; 1 barrier/step; Hb written f16.
__global__ __launch_bounds__(1024, 4) void k_rnn(const float* __restrict__ h0,
    const float* __restrict__ Wh, const float* __restrict__ xw,
    hf* __restrict__ Hb){
  __shared__ alignas(16) char hs[2*8192];   // [parity][16 rows x 512B]
  const int tid = threadIdx.x;
  const int w = tid >> 6, lane = tid & 63;
  const int c = lane & 15, q = lane >> 4;
  const int b0 = blockIdx.x * 16;
  const int col = w*16 + c;
  // ---- Wh B-frags: bw[kc][e] = Wh[kc*32+q*8+e][col] (one-time) ----
  hf8 bw[8];
  #pragma unroll
  for (int kc=0; kc<8; kc++){
    #pragma unroll
    for (int e=0; e<8; e++){
      bw[kc][e] = (hf)Wh[(kc*32 + q*8 + e)*256 + col];
    }
  }
  // ---- stage h0 -> hs[parity 0], swizzled ----
  if (tid < 512){
    int m = tid >> 5, s8 = tid & 31;           // row, 16B-slot
    const float* src = &h0[(b0 + m)*256 + s8*8];
    float4 d0 = *(const float4*)&src[0];
    float4 d1 = *(const float4*)&src[4];
    hf8 hv = {(hf)d0.x,(hf)d0.y,(hf)d0.z,(hf)d0.w,
              (hf)d1.x,(hf)d1.y,(hf)d1.z,(hf)d1.w};
    *(hf8*)&hs[m*512 + ((s8 ^ (m & 7)) << 4)] = hv;
  }
  // ---- prefetch xw for t=0 ----
  float xwv[4];
  #pragma unroll
  for (int r=0; r<4; r++) xwv[r] = xw[(b0 + q*4 + r)*256 + col];
  __syncthreads();
  const int m = c;                 // A-frag row (batch within block)
  const int abase = m*512;
  for (int t=0; t<128; t++){
    const int p = t & 1;
    // prefetch next step's xw (consumed next iteration -> latency hidden)
    float xwn[4];
    if (t < 127){
      #pragma unroll
      for (int r=0; r<4; r++) xwn[r] = xw[((t+1)*512 + b0 + q*4 + r)*256 + col];
    } else {
      #pragma unroll
      for (int r=0; r<4; r++) xwn[r] = 0.f;
    }
    // ---- A-frags from LDS (swizzled, conflict-free) ----
    hf8 a[8];
    #pragma unroll
    for (int kc=0; kc<8; kc++)
      a[kc] = *(const hf8*)&hs[p*8192 + abase + ((((kc<<2)|q) ^ (m & 7)) << 4)];
    // ---- MFMA: two independent 4-deep chains over k-halves ----
    f32x4 acca = (f32x4){0.f,0.f,0.f,0.f};
    f32x4 accb = (f32x4){0.f,0.f,0.f,0.f};
    #pragma unroll
    for (int kc=0; kc<4; kc++){
      acca = __builtin_amdgcn_mfma_f32_16x16x32_f16(a[kc],   bw[kc],   acca, 0,0,0);
      accb = __builtin_amdgcn_mfma_f32_16x16x32_f16(a[kc+4], bw[kc+4], accb, 0,0,0);
    }
    // ---- epilogue: tanh, write h -> LDS (other parity) + Hb(global, f16) ----
    #pragma unroll
    for (int r=0; r<4; r++){
      float v = acca[r] + accb[r] + xwv[r];
      float e2 = fast_exp2(v*C2L);
      float hn = 1.f - 2.f*fast_rcp(e2 + 1.f);
      int row = q*4 + r;
      *(hf*)&hs[(p^1)*8192 + row*512
                + (((col >> 3) ^ (row & 7)) << 4) + (col & 7)*2] = (hf)hn;
      Hb[(t*512 + b0 + row)*256 + col] = (hf)hn;
      xwv[r] = xwn[r];
    }
    __syncthreads();
  }
}

// ---------------- attention + softmax + scale ----------------
// grid (512 b, 4 t-tiles), 512 threads. Thread = (i, tau-quarter g of 32).
// P quarter in registers (8 float4 = 32 VGPR). Q tile (32 t) in LDS.
// 4-way rcp: w0/u+w1/v+w2/x+w3/y = (n01*d23+n23*d01)*rcp(d01*d23)
// -> 1 rcp per 4 taus. 4 timesteps per sweep; 2 barriers per sweep.
// No max in softmax (|e| <= sum|wv| ~ 5).
__global__ __launch_bounds__(512, 4) void k_attn(const float* __restrict__ P,
    const float* __restrict__ Qm, const float* __restrict__ Wv,
    const float* __restrict__ data, float* __restrict__ out){
  __shared__ alignas(16) float qs[32*128];          // [tt][tau] 16KB
  __shared__ alignas(16) float wvs[128];
  __shared__ alignas(16) float epart[2][4][4][128]; // [parity][quar][tl][i] 16KB
  __shared__ float red[2][4][2];                    // [parity][tl][half]
  const int b = blockIdx.x, tile = blockIdx.y;
  const int tid = threadIdx.x;
  const int i = tid & 127, g = tid >> 7;            // i, tau-quarter 0..3
  const int t0 = tile*32;
  if (tid < 128) wvs[tid] = -2.f*Wv[tid];
  #pragma unroll
  for (int v=0; v<2; v++){
    int flat = v*2048 + tid*4;
    int tt = flat >> 7, c = flat & 127;
    *(float4*)&qs[flat] = *(const float4*)&Qm[((t0+tt)*512 + b)*128 + c];
  }
  float4 p4[8];
  const float* prow = P + b*16384 + i*128 + g*32;
  #pragma unroll
  for (int v=0; v<8; v++) p4[v] = *(const float4*)&prow[v*4];
  __syncthreads();
  for (int tp=0; tp<8; tp++){
    const int pp = tp & 1;
    const float* qb  = &qs[(4*tp)*128 + g*32];
    const float* wvr = &wvs[g*32];
    float acc0=0.f, acc1=0.f, acc2=0.f, acc3=0.f;
    #pragma unroll
    for (int mm=0; mm<8; mm++){
      float4 Pv = p4[mm];
      float4 wv = *(const float4*)&wvr[mm*4];
      #pragma unroll
      for (int tl=0; tl<4; tl++){
        float4 qq = *(const float4*)&qb[tl*128 + mm*4];
        float u = fmaf(Pv.x, qq.x, 1.f), v = fmaf(Pv.y, qq.y, 1.f);
        float x = fmaf(Pv.z, qq.z, 1.f), y = fmaf(Pv.w, qq.w, 1.f);
        float d01 = u*v, d23 = x*y;
        float n01 = fmaf(wv.x, v, wv.y*u);
        float n23 = fmaf(wv.z, y, wv.w*x);
        float N = fmaf(n01, d23, n23*d01);
        float r = fast_rcp(d01*d23);
        float term = N*r;
        if (tl==0) acc0 += term;
        else if (tl==1) acc1 += term;
        else if (tl==2) acc2 += term;
        else acc3 += term;
      }
    }
    epart[pp][g][0][i] = acc0;
    epart[pp][g][1][i] = acc1;
    epart[pp][g][2][i] = acc2;
    epart[pp][g][3][i] = acc3;
    __syncthreads();
    // thread handles tl = g for the reduction + output
    float e = epart[pp][0][g][i] + epart[pp][1][g][i]
            + epart[pp][2][g][i] + epart[pp][3][g][i];
    float pe = fast_exp2(e*L2E);
    float sm = pe;
    #pragma unroll
    for (int off=32; off; off>>=1) sm += __shfl_xor(sm, off);
    if ((tid & 63) == 0) red[pp][g][(tid>>6)&1] = sm;
    __syncthreads();
    float ssum = red[pp][g][0] + red[pp][g][1];
    float alpha = pe * fast_rcp(ssum);
    int t = t0 + 4*tp + g;
    int base = (t*512 + b)*128 + i;
    out[base] = data[base]*alpha;
  }
}

extern "C" void kernel_launch(void* const* d_in, const int* in_sizes, int n_in,
                              void* d_out, int out_size, void* d_ws, size_t ws_size,
                              hipStream_t stream) {
  const float* data = (const float*)d_in[0];
  const float* h0   = (const float*)d_in[1];
  const float* Wx   = (const float*)d_in[2];
  const float* Wh   = (const float*)d_in[3];
  const float* bb   = (const float*)d_in[4];
  const float* W1   = (const float*)d_in[5];
  const float* b1   = (const float*)d_in[6];
  const float* W2   = (const float*)d_in[7];
  const float* b2   = (const float*)d_in[8];
  const float* Wv   = (const float*)d_in[9];
  // d_in[10] = bv: softmax-invariant constant, dropped. d_in[11] = n (128).
  float* wsp = (float*)d_ws;
  float* P   = wsp;                         //  8,388,608 f
  float* xwQ = wsp + 8388608;               // 16,777,216 f (xw, then reused as Q)
  hf*    Hbf = (hf*)(wsp + 25165824);       // 16,777,216 hf
  hf*    wts = (hf*)(wsp + 33554432);       // 81,920 hf
  const hf* Wxt = wts;                      // [256][128]
  const hf* W2t = wts + 32768;              // [128][256]
  const hf* W1t = wts + 65536;              // [128][128]
  float* out = (float*)d_out;

  hipLaunchKernelGGL(k_prep_w, dim3(320), dim3(256), 0, stream, Wx, W2, W1, wts);
  hipLaunchKernelGGL((k_gemm<128,0>), dim3(1024,2), dim3(256), 0, stream,
                     (const void*)data, Wxt, bb, xwQ);
  hipLaunchKernelGGL((k_gemm<128,2>), dim3(1024),   dim3(256), 0, stream,
                     (const void*)data, W1t, b1, P);
  hipLaunchKernelGGL(k_rnn, dim3(32), dim3(1024), 0, stream, h0, Wh, xwQ, Hbf);
  hipLaunchKernelGGL((k_gemm<256,1>), dim3(1024),   dim3(256), 0, stream,
                     (const void*)Hbf, W2t, b2, xwQ);
  hipLaunchKernelGGL(k_attn, dim3(512, 4), dim3(512), 0, stream, P, xwQ, Wv, data, out);
}